// Round 23
// baseline (49.142 us; speedup 1.0000x reference)
//
#include <hip/hip_runtime.h>
#include <hip/hip_fp16.h>

// Problem constants
#define NB 4      // batch
#define CI 256    // input channels
#define HH 64
#define WW 64
#define MC 64     // compressed channels
#define HS 128    // H*2
#define WS_ 128   // W*2
#define HW 4096   // HH*WW

typedef __attribute__((ext_vector_type(8))) short short8v;   // 8 bf16 (4 VGPRs)
typedef __attribute__((ext_vector_type(4))) float floatx4;   // MFMA C/D

__device__ inline unsigned short f2bf(float f) {
  union { float f; unsigned u; } v; v.f = f;
  unsigned r = v.u + 0x7FFFu + ((v.u >> 16) & 1u);   // RNE
  return (unsigned short)(r >> 16);
}

// ---------------------------------------------------------------------------
// Prep: rearrange weights into MFMA A-fragment layout (bf16).
// ---------------------------------------------------------------------------
__global__ __launch_bounds__(256) void prep_kernel(
    const float* __restrict__ w_comp, const float* __restrict__ w_enc,
    unsigned short* __restrict__ Aw1, unsigned short* __restrict__ Aw2) {
  int i = blockIdx.x * 256 + threadIdx.x;
  if (i < 16384) {                       // 8*64*32
    int kl = i & 31, o = (i >> 5) & 63, ks = i >> 11;
    Aw1[i] = f2bf(w_comp[o * 256 + ks * 32 + kl]);
  } else if (i < 16384 + 64512) {        // 18*112*32
    int j = i - 16384;
    int kl = j & 31, o = (j >> 5) % 112, ks = (j >> 5) / 112;
    int t = ks >> 1, m = (ks & 1) * 32 + kl;
    Aw2[j] = (o < 100) ? f2bf(w_enc[o * 576 + m * 9 + t]) : (unsigned short)0;
  }
}

// ---------------------------------------------------------------------------
// Kernel 1: 1x1 conv via MFMA, K-split 4 (round-10 version, unchanged).
// ---------------------------------------------------------------------------
__global__ __launch_bounds__(512, 1) void conv1x1_mfma(
    const float* __restrict__ x, const unsigned short* __restrict__ Aw1,
    const float* __restrict__ b_comp, unsigned short* __restrict__ comp_cl) {
  __shared__ float pacc[2][64][49];
  int tid = threadIdx.x;
  int wid = tid >> 6, lane = tid & 63;
  int tileid = wid & 1, kh = wid >> 1;    // kh 0..3
  int Nt = blockIdx.x * 2 + tileid;       // 0..1023
  int n = Nt >> 8, pixbase = (Nt & 255) * 16;
  int l15 = lane & 15, g = lane >> 4;
  int pix = pixbase + l15;

  floatx4 acc[4];
#pragma unroll
  for (int ot = 0; ot < 4; ++ot) acc[ot] = (floatx4){0.f, 0.f, 0.f, 0.f};

  const float* xb = x + (size_t)n * CI * HW + pix;
  const unsigned short* ab = Aw1 + l15 * 32 + g * 8;

#pragma unroll
  for (int s = 0; s < 2; ++s) {
    int ks = kh * 2 + s;
    int c0 = ks * 32 + g * 8;
    short8v bfrag;
#pragma unroll
    for (int j = 0; j < 8; ++j)
      bfrag[j] = (short)f2bf(xb[(size_t)(c0 + j) * HW]);
#pragma unroll
    for (int ot = 0; ot < 4; ++ot) {
      short8v af = *(const short8v*)(ab + (ks * 64 + ot * 16) * 32);
      acc[ot] = __builtin_amdgcn_mfma_f32_16x16x32_bf16(af, bfrag, acc[ot], 0, 0, 0);
    }
  }

  if (kh > 0) {
#pragma unroll
    for (int ot = 0; ot < 4; ++ot)
#pragma unroll
      for (int r = 0; r < 4; ++r)
        pacc[tileid][lane][(kh - 1) * 16 + ot * 4 + r] = acc[ot][r];
  }
  __syncthreads();
  if (kh == 0) {
    unsigned short* cp = comp_cl + ((size_t)(n * HW + pix)) * 64;
#pragma unroll
    for (int ot = 0; ot < 4; ++ot) {
      const float4 bv = *(const float4*)(b_comp + ot * 16 + g * 4);
      float v0 = acc[ot][0] + bv.x, v1 = acc[ot][1] + bv.y;
      float v2 = acc[ot][2] + bv.z, v3 = acc[ot][3] + bv.w;
#pragma unroll
      for (int sl = 0; sl < 3; ++sl) {
        v0 += pacc[tileid][lane][sl * 16 + ot * 4 + 0];
        v1 += pacc[tileid][lane][sl * 16 + ot * 4 + 1];
        v2 += pacc[tileid][lane][sl * 16 + ot * 4 + 2];
        v3 += pacc[tileid][lane][sl * 16 + ot * 4 + 3];
      }
      unsigned h01 = (unsigned)f2bf(v0) | ((unsigned)f2bf(v1) << 16);
      unsigned h23 = (unsigned)f2bf(v2) | ((unsigned)f2bf(v3) << 16);
      *(int2*)(cp + ot * 16 + g * 4) = make_int2((int)h01, (int)h23);
    }
  }
}

// ---------------------------------------------------------------------------
// Kernel 2 (FUSED, r22 + clean depth-2 pipeline):
// Same 20-col halo staging, same T1 XCD swizzle; phase 2 now uses 3
// rotating f16 buffers with loads issued TWO stages ahead.
// ---------------------------------------------------------------------------
#define PKLO(W, D, ACC)                                                        \
  asm("v_pk_fma_f16 %0, %1, %2, %0 op_sel:[0,0,0] op_sel_hi:[1,0,1]"           \
      : "+v"(ACC) : "v"(W), "v"(D));
#define PKHI(W, D, ACC)                                                        \
  asm("v_pk_fma_f16 %0, %1, %2, %0 op_sel:[0,1,0] op_sel_hi:[1,1,1]"           \
      : "+v"(ACC) : "v"(W), "v"(D));

// Row: 6 patch f16 (3 dwords). px0 taps j=0..4 = v0..v4; px1 = v1..v5.
#define ROWPK(WA, WB, WC, WD, WE, VA, VB, VC, VD, VE, RP)                      \
  { const unsigned* rr = (const unsigned*)(RP);                                \
    unsigned d0 = rr[0], d1 = rr[1], d2 = rr[2];                               \
    PKLO(WA, d0, aA) PKHI(WB, d0, aA) PKLO(WC, d1, aA)                         \
    PKHI(WD, d1, aA) PKLO(WE, d2, aA)                                          \
    PKHI(VA, d0, aB) PKLO(VB, d1, aB) PKHI(VC, d1, aB)                         \
    PKLO(VD, d2, aB) PKHI(VE, d2, aB) }

// slot f in [0,960): c = f/30 (32 ch), r = (f%30)/5, h = f%5 (4-wide cols)
__device__ __forceinline__ float4 load_slot20(const float* __restrict__ xb,
                                              int h0, int w0, int f,
                                              bool interior) {
  int c = f / 30, rem = f - c * 30, r = rem / 5, h = rem - r * 5;
  int gh = h0 - 2 + r, gw = w0 - 2 + h * 4;
  if (interior) {
    const float* gp = xb + (size_t)c * HW + gh * WW + gw;
    float2 lo = *(const float2*)gp;       // gw even -> 8B aligned
    float2 hi = *(const float2*)(gp + 2);
    return make_float4(lo.x, lo.y, hi.x, hi.y);
  }
  int ghc = min(max(gh, 0), 63);
  const float* rowp = xb + (size_t)c * HW + ghc * WW;
  float v0 = rowp[min(max(gw + 0, 0), 63)];
  float v1 = rowp[min(max(gw + 1, 0), 63)];
  float v2 = rowp[min(max(gw + 2, 0), 63)];
  float v3 = rowp[min(max(gw + 3, 0), 63)];
  bool rok = ((unsigned)gh < 64u);
  v0 = (rok && (unsigned)(gw + 0) < 64u) ? v0 : 0.f;
  v1 = (rok && (unsigned)(gw + 1) < 64u) ? v1 : 0.f;
  v2 = (rok && (unsigned)(gw + 2) < 64u) ? v2 : 0.f;
  v3 = (rok && (unsigned)(gw + 3) < 64u) ? v3 : 0.f;
  return make_float4(v0, v1, v2, v3);
}

__device__ __forceinline__ uint2 f4_to_h4(float4 s) {
  __half2 a = __floats2half2_rn(s.x, s.y);
  __half2 b = __floats2half2_rn(s.z, s.w);
  return make_uint2(*(unsigned*)&a, *(unsigned*)&b);
}

__global__ __launch_bounds__(512, 4) void fused_kernel(
    const float* __restrict__ x,
    const unsigned short* __restrict__ comp_cl,
    const unsigned short* __restrict__ Aw2,
    const float* __restrict__ b_enc,
    float* __restrict__ out) {
  __shared__ float smem[12672];                 // 50,688 B
  float* paccF = smem;                          // phase 1: [2][64][85]
  // phase 2: THREE f16 buffers [32][120] = 3840 fp16 = 7680 B each (union)
  unsigned short* xph = (unsigned short*)smem;
  unsigned int* wlds = (unsigned int*)(smem + 10880);   // [2][2][16][28]

  int tid = threadIdx.x;
  int bid = blockIdx.x;
  // T1 XCD swizzle: contiguous 64-block chunk per XCD, tyi fastest-varying
  int swz = (bid & 7) * 64 + (bid >> 3);        // bijective for 512 blocks
  int n = swz >> 7;                             // batch
  int tyi = swz & 31;                           // row tile (fastest)
  int txi = (swz >> 5) & 3;                     // col tile
  int ty0 = tyi * 4, tx0 = txi * 32;
  int h0 = tyi * 2, w0 = txi * 16;      // input core base (2 rows x 16 cols)

  int wid = tid >> 6, lane = tid & 63;
  int tileid = wid & 1, kh = wid >> 1;  // row-wave, K-quarter
  int l15 = lane & 15, g = lane >> 4;

  bool interior = (tyi >= 1) && (tyi <= 30) && (txi >= 1) && (txi <= 2);
  bool extra = tid < 448;               // 960 = 512 + 448 slots per stage

  // pre-issue stage-0 x loads (hide HBM latency under phase 1)
  const float* xb0g = x + (size_t)(n * CI) * HW;
  float4 pre0f = load_slot20(xb0g, h0, w0, tid, interior);
  float4 pre1f = extra ? load_slot20(xb0g, h0, w0, tid + 512, interior)
                       : make_float4(0.f, 0.f, 0.f, 0.f);

  // ================= phase 1: kenc for the 2x16 core px ====================
  {
    int pix = (h0 + tileid) * 64 + w0 + l15;
    int y = pix >> 6, xcol = pix & 63;

    bool vm[9];
    int sh9[9];
#pragma unroll
    for (int t = 0; t < 9; ++t) {
      int dy = t / 3, dx = t % 3;
      vm[t] = ((unsigned)(y + dy - 1) < 64u) && ((unsigned)(xcol + dx - 1) < 64u);
      sh9[t] = (dy - 1) * 64 + (dx - 1);
    }

    floatx4 acc[7];
#pragma unroll
    for (int ot = 0; ot < 7; ++ot) acc[ot] = (floatx4){0.f, 0.f, 0.f, 0.f};

    const unsigned short* cb = comp_cl + (size_t)n * HW * 64;
    const unsigned short* ab = Aw2 + l15 * 32 + g * 8;
    const short8v zv = {0, 0, 0, 0, 0, 0, 0, 0};

    int ks0 = (kh < 2) ? kh * 5 : 10 + (kh - 2) * 4;
    int len = (kh < 2) ? 5 : 4;

    // prefetch all 5 bfrags (clamped idx; unused slot skipped)
    short8v bf[5];
#pragma unroll
    for (int s = 0; s < 5; ++s) {
      int ks = ks0 + s; if (ks > 17) ks = 17;
      int t = ks >> 1, mh = ks & 1;
      const unsigned short* bp = cb + (pix + sh9[t]) * 64 + mh * 32 + g * 8;
      bf[s] = vm[t] ? *(const short8v*)bp : zv;
    }

#pragma unroll
    for (int s = 0; s < 5; ++s) {
      if (s < len) {
        int ks = ks0 + s;
#pragma unroll
        for (int ot = 0; ot < 7; ++ot) {
          short8v af = *(const short8v*)(ab + (ks * 112 + ot * 16) * 32);
          acc[ot] = __builtin_amdgcn_mfma_f32_16x16x32_bf16(af, bf[s], acc[ot], 0, 0, 0);
        }
      }
    }

    if (kh > 0) {
#pragma unroll
      for (int ot = 0; ot < 7; ++ot)
#pragma unroll
        for (int r = 0; r < 4; ++r)
          paccF[(tileid * 64 + lane) * 85 + (kh - 1) * 28 + ot * 4 + r] =
              acc[ot][r];
    }
    __syncthreads();
    if (kh == 0) {
#pragma unroll
      for (int ot = 0; ot < 7; ++ot) {
        int ob = ot * 16 + g * 4; if (ob > 96) ob = 96;
        const float4 bv = *(const float4*)(b_enc + ob);
        acc[ot][0] += bv.x; acc[ot][1] += bv.y;
        acc[ot][2] += bv.z; acc[ot][3] += bv.w;
#pragma unroll
        for (int sl = 0; sl < 3; ++sl) {
          acc[ot][0] += paccF[(tileid * 64 + lane) * 85 + sl * 28 + ot * 4 + 0];
          acc[ot][1] += paccF[(tileid * 64 + lane) * 85 + sl * 28 + ot * 4 + 1];
          acc[ot][2] += paccF[(tileid * 64 + lane) * 85 + sl * 28 + ot * 4 + 2];
          acc[ot][3] += paccF[(tileid * 64 + lane) * 85 + sl * 28 + ot * 4 + 3];
        }
      }

      // per-r softmax; normalized values back into acc[ot][r]
#pragma unroll
      for (int r = 0; r < 4; ++r) {
        float m = acc[0][r];
#pragma unroll
        for (int ot = 1; ot < 6; ++ot) m = fmaxf(m, acc[ot][r]);
        if (g == 0) m = fmaxf(m, acc[6][r]);
        m = fmaxf(m, __shfl_xor(m, 16));
        m = fmaxf(m, __shfl_xor(m, 32));
        float s = 0.f;
        float e[7];
#pragma unroll
        for (int ot = 0; ot < 7; ++ot) {
          bool val = (ot < 6) || (g == 0);
          e[ot] = val ? __expf(acc[ot][r] - m) : 0.f;
          s += e[ot];
        }
        s += __shfl_xor(s, 16);
        s += __shfl_xor(s, 32);
        float inv = 1.f / s;
#pragma unroll
        for (int ot = 0; ot < 7; ++ot) acc[ot][r] = e[ot] * inv;
      }

      // pack f16 pairs into LDS: wlds[sh][row=tileid][px=l15][k=ot*4+g]
#pragma unroll
      for (int sh = 0; sh < 2; ++sh) {
        unsigned int* wq = wlds + sh * 896 + tileid * 448 + l15 * 28;
#pragma unroll
        for (int ot = 0; ot < 7; ++ot) {
          if ((ot < 6) || (g == 0)) {
            __half2 h2 = __floats2half2_rn(acc[ot][2 * sh], acc[ot][2 * sh + 1]);
            wq[ot * 4 + g] = *reinterpret_cast<unsigned int*>(&h2);
          }
        }
      }
    }
  }
  __syncthreads();   // wlds complete; paccF dead

  // ========= phase 2: depth-2 pipelined reassembly, 8 x 32-ch stages =======
  int cslot = tid >> 5;                 // 0..15
  int rem = tid & 31;
  int py = rem >> 4;                    // input row 0..1
  int shsel = (rem >> 3) & 1;           // output sub-row
  int pxp = rem & 7;                    // input col pair 0..7
  int oy = ty0 + 2 * py + shsel;
  int ox0 = tx0 + 4 * pxp;
  int cb0 = 2 * pxp;                    // halo col base (even fp16 -> 4B algn)

  // weights: 2 adjacent px, ONE sh plane = 50 packed dwords (named uint4s)
  const unsigned int* wtA = wlds + shsel * 896 + py * 448 + cb0 * 28;
  const unsigned int* wtB = wtA + 28;
  uint4 A0 = *(const uint4*)(wtA + 0);
  uint4 A1 = *(const uint4*)(wtA + 4);
  uint4 A2 = *(const uint4*)(wtA + 8);
  uint4 A3 = *(const uint4*)(wtA + 12);
  uint4 A4 = *(const uint4*)(wtA + 16);
  uint4 A5 = *(const uint4*)(wtA + 20);
  unsigned int A6 = wtA[24];
  uint4 B0 = *(const uint4*)(wtB + 0);
  uint4 B1 = *(const uint4*)(wtB + 4);
  uint4 B2 = *(const uint4*)(wtB + 8);
  uint4 B3 = *(const uint4*)(wtB + 12);
  uint4 B4 = *(const uint4*)(wtB + 16);
  uint4 B5 = *(const uint4*)(wtB + 20);
  unsigned int B6 = wtB[24];

  // write pre-issued stage 0 (f16) into buffer 0 (paccF dead now);
  // issue stage-1 loads and HOLD them (written next iteration).
  *(uint2*)(xph + 4 * tid) = f4_to_h4(pre0f);
  if (extra) *(uint2*)(xph + 4 * (tid + 512)) = f4_to_h4(pre1f);

  float4 hA, hB;                        // stage cs+1 data in flight
  {
    const float* xb1 = x + (size_t)(n * CI + 32) * HW;
    hA = load_slot20(xb1, h0, w0, tid, interior);
    hB = extra ? load_slot20(xb1, h0, w0, tid + 512, interior)
               : make_float4(0.f, 0.f, 0.f, 0.f);
  }
  __syncthreads();

  for (int cs = 0; cs < 8; ++cs) {
    unsigned short* xpcur = xph + (cs % 3) * 3840;
    unsigned short* xpnxt = xph + ((cs + 1) % 3) * 3840;

    // issue loads for stage cs+2 (two stages of latency slack)
    float4 lA = make_float4(0.f, 0.f, 0.f, 0.f);
    float4 lB = lA;
    if (cs < 6) {
      const float* xbn = x + (size_t)(n * CI + (cs + 2) * 32) * HW;
      lA = load_slot20(xbn, h0, w0, tid, interior);
      if (extra) lB = load_slot20(xbn, h0, w0, tid + 512, interior);
    }

    // compute current stage: 2 channel-iters, packed-f16 accumulate
    float* outb = out + ((size_t)(n * CI + cs * 32) * HS + oy) * WS_ + ox0;
#pragma unroll
    for (int it = 0; it < 2; ++it) {
      int cl = it * 16 + cslot;
      const unsigned short* p = xpcur + cl * 120 + py * 20 + cb0;
      unsigned aA = 0u, aB = 0u;        // packed f16 {sw0, sw1} accumulators
      ROWPK(A0.x, A0.y, A0.z, A0.w, A1.x, B0.x, B0.y, B0.z, B0.w, B1.x, p)
      ROWPK(A1.y, A1.z, A1.w, A2.x, A2.y, B1.y, B1.z, B1.w, B2.x, B2.y, p + 20)
      ROWPK(A2.z, A2.w, A3.x, A3.y, A3.z, B2.z, B2.w, B3.x, B3.y, B3.z, p + 40)
      ROWPK(A3.w, A4.x, A4.y, A4.z, A4.w, B3.w, B4.x, B4.y, B4.z, B4.w, p + 60)
      ROWPK(A5.x, A5.y, A5.z, A5.w, A6,   B5.x, B5.y, B5.z, B5.w, B6,   p + 80)
      __half2 hA2 = *reinterpret_cast<__half2*>(&aA);
      __half2 hB2 = *reinterpret_cast<__half2*>(&aB);
      float2 fA = __half22float2(hA2);
      float2 fB = __half22float2(hB2);
      *(float4*)(outb + (size_t)cl * HS * WS_) =
          make_float4(fA.x, fA.y, fB.x, fB.y);
    }

    // write stage cs+1 (held data, loaded one iter ago), barrier, rotate
    if (cs < 7) {
      *(uint2*)(xpnxt + 4 * tid) = f4_to_h4(hA);
      if (extra) *(uint2*)(xpnxt + 4 * (tid + 512)) = f4_to_h4(hB);
      __syncthreads();
    }
    hA = lA; hB = lB;
  }
}

// ---------------------------------------------------------------------------
extern "C" void kernel_launch(void* const* d_in, const int* in_sizes, int n_in,
                              void* d_out, int out_size, void* d_ws,
                              size_t ws_size, hipStream_t stream) {
  const float* x      = (const float*)d_in[0];
  const float* w_comp = (const float*)d_in[1];
  const float* b_comp = (const float*)d_in[2];
  const float* w_enc  = (const float*)d_in[3];
  const float* b_enc  = (const float*)d_in[4];
  float* out = (float*)d_out;

  char* ws = (char*)d_ws;
  unsigned short* comp_cl = (unsigned short*)ws;                  // 2,097,152 B
  unsigned short* Aw1     = (unsigned short*)(ws + 2097152);      //    32,768 B
  unsigned short* Aw2     = (unsigned short*)(ws + 2129920);      //   129,024 B

  prep_kernel<<<dim3(316), 256, 0, stream>>>(w_comp, w_enc, Aw1, Aw2);
  conv1x1_mfma<<<dim3(512), 512, 0, stream>>>(x, Aw1, b_comp, comp_cl);
  fused_kernel<<<dim3(512), 512, 0, stream>>>(x, comp_cl, Aw2, b_enc, out);
}

// Round 24
// 48.404 us; speedup vs baseline: 1.0153x; 1.0153x over previous
//
#include <hip/hip_runtime.h>
#include <hip/hip_fp16.h>

// Problem constants
#define NB 4      // batch
#define CI 256    // input channels
#define HH 64
#define WW 64
#define MC 64     // compressed channels
#define HS 128    // H*2
#define WS_ 128   // W*2
#define HW 4096   // HH*WW

typedef __attribute__((ext_vector_type(8))) short short8v;   // 8 bf16 (4 VGPRs)
typedef __attribute__((ext_vector_type(4))) float floatx4;   // MFMA C/D

__device__ inline unsigned short f2bf(float f) {
  union { float f; unsigned u; } v; v.f = f;
  unsigned r = v.u + 0x7FFFu + ((v.u >> 16) & 1u);   // RNE
  return (unsigned short)(r >> 16);
}

// ---------------------------------------------------------------------------
// Prep: rearrange weights into MFMA A-fragment layout (bf16).
// ---------------------------------------------------------------------------
__global__ __launch_bounds__(256) void prep_kernel(
    const float* __restrict__ w_comp, const float* __restrict__ w_enc,
    unsigned short* __restrict__ Aw1, unsigned short* __restrict__ Aw2) {
  int i = blockIdx.x * 256 + threadIdx.x;
  if (i < 16384) {                       // 8*64*32
    int kl = i & 31, o = (i >> 5) & 63, ks = i >> 11;
    Aw1[i] = f2bf(w_comp[o * 256 + ks * 32 + kl]);
  } else if (i < 16384 + 64512) {        // 18*112*32
    int j = i - 16384;
    int kl = j & 31, o = (j >> 5) % 112, ks = (j >> 5) / 112;
    int t = ks >> 1, m = (ks & 1) * 32 + kl;
    Aw2[j] = (o < 100) ? f2bf(w_enc[o * 576 + m * 9 + t]) : (unsigned short)0;
  }
}

// ---------------------------------------------------------------------------
// Kernel 1: 1x1 conv via MFMA, K-split 4 (round-10 version).
// ---------------------------------------------------------------------------
__global__ __launch_bounds__(512, 1) void conv1x1_mfma(
    const float* __restrict__ x, const unsigned short* __restrict__ Aw1,
    const float* __restrict__ b_comp, unsigned short* __restrict__ comp_cl) {
  __shared__ float pacc[2][64][49];
  int tid = threadIdx.x;
  int wid = tid >> 6, lane = tid & 63;
  int tileid = wid & 1, kh = wid >> 1;    // kh 0..3
  int Nt = blockIdx.x * 2 + tileid;       // 0..1023
  int n = Nt >> 8, pixbase = (Nt & 255) * 16;
  int l15 = lane & 15, g = lane >> 4;
  int pix = pixbase + l15;

  floatx4 acc[4];
#pragma unroll
  for (int ot = 0; ot < 4; ++ot) acc[ot] = (floatx4){0.f, 0.f, 0.f, 0.f};

  const float* xb = x + (size_t)n * CI * HW + pix;
  const unsigned short* ab = Aw1 + l15 * 32 + g * 8;

#pragma unroll
  for (int s = 0; s < 2; ++s) {
    int ks = kh * 2 + s;
    int c0 = ks * 32 + g * 8;
    short8v bfrag;
#pragma unroll
    for (int j = 0; j < 8; ++j)
      bfrag[j] = (short)f2bf(xb[(size_t)(c0 + j) * HW]);
#pragma unroll
    for (int ot = 0; ot < 4; ++ot) {
      short8v af = *(const short8v*)(ab + (ks * 64 + ot * 16) * 32);
      acc[ot] = __builtin_amdgcn_mfma_f32_16x16x32_bf16(af, bfrag, acc[ot], 0, 0, 0);
    }
  }

  if (kh > 0) {
#pragma unroll
    for (int ot = 0; ot < 4; ++ot)
#pragma unroll
      for (int r = 0; r < 4; ++r)
        pacc[tileid][lane][(kh - 1) * 16 + ot * 4 + r] = acc[ot][r];
  }
  __syncthreads();
  if (kh == 0) {
    unsigned short* cp = comp_cl + ((size_t)(n * HW + pix)) * 64;
#pragma unroll
    for (int ot = 0; ot < 4; ++ot) {
      const float4 bv = *(const float4*)(b_comp + ot * 16 + g * 4);
      float v0 = acc[ot][0] + bv.x, v1 = acc[ot][1] + bv.y;
      float v2 = acc[ot][2] + bv.z, v3 = acc[ot][3] + bv.w;
#pragma unroll
      for (int sl = 0; sl < 3; ++sl) {
        v0 += pacc[tileid][lane][sl * 16 + ot * 4 + 0];
        v1 += pacc[tileid][lane][sl * 16 + ot * 4 + 1];
        v2 += pacc[tileid][lane][sl * 16 + ot * 4 + 2];
        v3 += pacc[tileid][lane][sl * 16 + ot * 4 + 3];
      }
      unsigned h01 = (unsigned)f2bf(v0) | ((unsigned)f2bf(v1) << 16);
      unsigned h23 = (unsigned)f2bf(v2) | ((unsigned)f2bf(v3) << 16);
      *(int2*)(cp + ot * 16 + g * 4) = make_int2((int)h01, (int)h23);
    }
  }
}

// ---------------------------------------------------------------------------
// Kernel 2 (FUSED, r22 optimum): kenc -> LDS weights -> depth-1 pipelined
// reassembly with v_pk_fma_f16, + T1 XCD swizzle (tyi fastest within XCD
// chunk -> vertical halo rows hit the same L2).
// ---------------------------------------------------------------------------
#define PKLO(W, D, ACC)                                                        \
  asm("v_pk_fma_f16 %0, %1, %2, %0 op_sel:[0,0,0] op_sel_hi:[1,0,1]"           \
      : "+v"(ACC) : "v"(W), "v"(D));
#define PKHI(W, D, ACC)                                                        \
  asm("v_pk_fma_f16 %0, %1, %2, %0 op_sel:[0,1,0] op_sel_hi:[1,1,1]"           \
      : "+v"(ACC) : "v"(W), "v"(D));

// Row: 6 patch f16 (3 dwords). px0 taps j=0..4 = v0..v4; px1 = v1..v5.
#define ROWPK(WA, WB, WC, WD, WE, VA, VB, VC, VD, VE, RP)                      \
  { const unsigned* rr = (const unsigned*)(RP);                                \
    unsigned d0 = rr[0], d1 = rr[1], d2 = rr[2];                               \
    PKLO(WA, d0, aA) PKHI(WB, d0, aA) PKLO(WC, d1, aA)                         \
    PKHI(WD, d1, aA) PKLO(WE, d2, aA)                                          \
    PKHI(VA, d0, aB) PKLO(VB, d1, aB) PKHI(VC, d1, aB)                         \
    PKLO(VD, d2, aB) PKHI(VE, d2, aB) }

// slot f in [0,960): c = f/30 (32 ch), r = (f%30)/5, h = f%5 (4-wide cols)
__device__ __forceinline__ float4 load_slot20(const float* __restrict__ xb,
                                              int h0, int w0, int f,
                                              bool interior) {
  int c = f / 30, rem = f - c * 30, r = rem / 5, h = rem - r * 5;
  int gh = h0 - 2 + r, gw = w0 - 2 + h * 4;
  if (interior) {
    const float* gp = xb + (size_t)c * HW + gh * WW + gw;
    float2 lo = *(const float2*)gp;       // gw even -> 8B aligned
    float2 hi = *(const float2*)(gp + 2);
    return make_float4(lo.x, lo.y, hi.x, hi.y);
  }
  int ghc = min(max(gh, 0), 63);
  const float* rowp = xb + (size_t)c * HW + ghc * WW;
  float v0 = rowp[min(max(gw + 0, 0), 63)];
  float v1 = rowp[min(max(gw + 1, 0), 63)];
  float v2 = rowp[min(max(gw + 2, 0), 63)];
  float v3 = rowp[min(max(gw + 3, 0), 63)];
  bool rok = ((unsigned)gh < 64u);
  v0 = (rok && (unsigned)(gw + 0) < 64u) ? v0 : 0.f;
  v1 = (rok && (unsigned)(gw + 1) < 64u) ? v1 : 0.f;
  v2 = (rok && (unsigned)(gw + 2) < 64u) ? v2 : 0.f;
  v3 = (rok && (unsigned)(gw + 3) < 64u) ? v3 : 0.f;
  return make_float4(v0, v1, v2, v3);
}

__device__ __forceinline__ uint2 f4_to_h4(float4 s) {
  __half2 a = __floats2half2_rn(s.x, s.y);
  __half2 b = __floats2half2_rn(s.z, s.w);
  return make_uint2(*(unsigned*)&a, *(unsigned*)&b);
}

__global__ __launch_bounds__(512, 4) void fused_kernel(
    const float* __restrict__ x,
    const unsigned short* __restrict__ comp_cl,
    const unsigned short* __restrict__ Aw2,
    const float* __restrict__ b_enc,
    float* __restrict__ out) {
  __shared__ float smem[12672];                 // 50,688 B
  float* paccF = smem;                          // phase 1: [2][64][85]
  // phase 2: two f16 buffers [32][120] = 3840 fp16 = 7680 B each (union)
  unsigned short* xph = (unsigned short*)smem;
  unsigned int* wlds = (unsigned int*)(smem + 10880);   // [2][2][16][28]

  int tid = threadIdx.x;
  int bid = blockIdx.x;
  // T1 XCD swizzle: contiguous 64-block chunk per XCD, tyi fastest-varying
  int swz = (bid & 7) * 64 + (bid >> 3);        // bijective for 512 blocks
  int n = swz >> 7;                             // batch
  int tyi = swz & 31;                           // row tile (fastest)
  int txi = (swz >> 5) & 3;                     // col tile
  int ty0 = tyi * 4, tx0 = txi * 32;
  int h0 = tyi * 2, w0 = txi * 16;      // input core base (2 rows x 16 cols)

  int wid = tid >> 6, lane = tid & 63;
  int tileid = wid & 1, kh = wid >> 1;  // row-wave, K-quarter
  int l15 = lane & 15, g = lane >> 4;

  bool interior = (tyi >= 1) && (tyi <= 30) && (txi >= 1) && (txi <= 2);
  bool extra = tid < 448;               // 960 = 512 + 448 slots per stage

  // pre-issue stage-0 x loads (hide HBM latency under phase 1)
  const float* xb0g = x + (size_t)(n * CI) * HW;
  float4 pre0f = load_slot20(xb0g, h0, w0, tid, interior);
  float4 pre1f = extra ? load_slot20(xb0g, h0, w0, tid + 512, interior)
                       : make_float4(0.f, 0.f, 0.f, 0.f);

  // ================= phase 1: kenc for the 2x16 core px ====================
  {
    int pix = (h0 + tileid) * 64 + w0 + l15;
    int y = pix >> 6, xcol = pix & 63;

    bool vm[9];
    int sh9[9];
#pragma unroll
    for (int t = 0; t < 9; ++t) {
      int dy = t / 3, dx = t % 3;
      vm[t] = ((unsigned)(y + dy - 1) < 64u) && ((unsigned)(xcol + dx - 1) < 64u);
      sh9[t] = (dy - 1) * 64 + (dx - 1);
    }

    floatx4 acc[7];
#pragma unroll
    for (int ot = 0; ot < 7; ++ot) acc[ot] = (floatx4){0.f, 0.f, 0.f, 0.f};

    const unsigned short* cb = comp_cl + (size_t)n * HW * 64;
    const unsigned short* ab = Aw2 + l15 * 32 + g * 8;
    const short8v zv = {0, 0, 0, 0, 0, 0, 0, 0};

    int ks0 = (kh < 2) ? kh * 5 : 10 + (kh - 2) * 4;
    int len = (kh < 2) ? 5 : 4;

    // prefetch all 5 bfrags (clamped idx; unused slot skipped)
    short8v bf[5];
#pragma unroll
    for (int s = 0; s < 5; ++s) {
      int ks = ks0 + s; if (ks > 17) ks = 17;
      int t = ks >> 1, mh = ks & 1;
      const unsigned short* bp = cb + (pix + sh9[t]) * 64 + mh * 32 + g * 8;
      bf[s] = vm[t] ? *(const short8v*)bp : zv;
    }

#pragma unroll
    for (int s = 0; s < 5; ++s) {
      if (s < len) {
        int ks = ks0 + s;
#pragma unroll
        for (int ot = 0; ot < 7; ++ot) {
          short8v af = *(const short8v*)(ab + (ks * 112 + ot * 16) * 32);
          acc[ot] = __builtin_amdgcn_mfma_f32_16x16x32_bf16(af, bf[s], acc[ot], 0, 0, 0);
        }
      }
    }

    if (kh > 0) {
#pragma unroll
      for (int ot = 0; ot < 7; ++ot)
#pragma unroll
        for (int r = 0; r < 4; ++r)
          paccF[(tileid * 64 + lane) * 85 + (kh - 1) * 28 + ot * 4 + r] =
              acc[ot][r];
    }
    __syncthreads();
    if (kh == 0) {
#pragma unroll
      for (int ot = 0; ot < 7; ++ot) {
        int ob = ot * 16 + g * 4; if (ob > 96) ob = 96;
        const float4 bv = *(const float4*)(b_enc + ob);
        acc[ot][0] += bv.x; acc[ot][1] += bv.y;
        acc[ot][2] += bv.z; acc[ot][3] += bv.w;
#pragma unroll
        for (int sl = 0; sl < 3; ++sl) {
          acc[ot][0] += paccF[(tileid * 64 + lane) * 85 + sl * 28 + ot * 4 + 0];
          acc[ot][1] += paccF[(tileid * 64 + lane) * 85 + sl * 28 + ot * 4 + 1];
          acc[ot][2] += paccF[(tileid * 64 + lane) * 85 + sl * 28 + ot * 4 + 2];
          acc[ot][3] += paccF[(tileid * 64 + lane) * 85 + sl * 28 + ot * 4 + 3];
        }
      }

      // per-r softmax; normalized values back into acc[ot][r]
#pragma unroll
      for (int r = 0; r < 4; ++r) {
        float m = acc[0][r];
#pragma unroll
        for (int ot = 1; ot < 6; ++ot) m = fmaxf(m, acc[ot][r]);
        if (g == 0) m = fmaxf(m, acc[6][r]);
        m = fmaxf(m, __shfl_xor(m, 16));
        m = fmaxf(m, __shfl_xor(m, 32));
        float s = 0.f;
        float e[7];
#pragma unroll
        for (int ot = 0; ot < 7; ++ot) {
          bool val = (ot < 6) || (g == 0);
          e[ot] = val ? __expf(acc[ot][r] - m) : 0.f;
          s += e[ot];
        }
        s += __shfl_xor(s, 16);
        s += __shfl_xor(s, 32);
        float inv = 1.f / s;
#pragma unroll
        for (int ot = 0; ot < 7; ++ot) acc[ot][r] = e[ot] * inv;
      }

      // pack f16 pairs into LDS: wlds[sh][row=tileid][px=l15][k=ot*4+g]
#pragma unroll
      for (int sh = 0; sh < 2; ++sh) {
        unsigned int* wq = wlds + sh * 896 + tileid * 448 + l15 * 28;
#pragma unroll
        for (int ot = 0; ot < 7; ++ot) {
          if ((ot < 6) || (g == 0)) {
            __half2 h2 = __floats2half2_rn(acc[ot][2 * sh], acc[ot][2 * sh + 1]);
            wq[ot * 4 + g] = *reinterpret_cast<unsigned int*>(&h2);
          }
        }
      }
    }
  }
  __syncthreads();   // wlds complete; paccF dead

  // ================= phase 2: pipelined reassembly, 8 x 32-ch stages =======
  int cslot = tid >> 5;                 // 0..15
  int rem = tid & 31;
  int py = rem >> 4;                    // input row 0..1
  int shsel = (rem >> 3) & 1;           // output sub-row
  int pxp = rem & 7;                    // input col pair 0..7
  int oy = ty0 + 2 * py + shsel;
  int ox0 = tx0 + 4 * pxp;
  int cb0 = 2 * pxp;                    // halo col base (even fp16 -> 4B algn)

  // weights: 2 adjacent px, ONE sh plane = 50 packed dwords (named uint4s)
  const unsigned int* wtA = wlds + shsel * 896 + py * 448 + cb0 * 28;
  const unsigned int* wtB = wtA + 28;
  uint4 A0 = *(const uint4*)(wtA + 0);
  uint4 A1 = *(const uint4*)(wtA + 4);
  uint4 A2 = *(const uint4*)(wtA + 8);
  uint4 A3 = *(const uint4*)(wtA + 12);
  uint4 A4 = *(const uint4*)(wtA + 16);
  uint4 A5 = *(const uint4*)(wtA + 20);
  unsigned int A6 = wtA[24];
  uint4 B0 = *(const uint4*)(wtB + 0);
  uint4 B1 = *(const uint4*)(wtB + 4);
  uint4 B2 = *(const uint4*)(wtB + 8);
  uint4 B3 = *(const uint4*)(wtB + 12);
  uint4 B4 = *(const uint4*)(wtB + 16);
  uint4 B5 = *(const uint4*)(wtB + 20);
  unsigned int B6 = wtB[24];

  // write pre-issued stage 0 (f16) into buffer 0 (paccF dead now)
  {
    uint2 p0 = f4_to_h4(pre0f);
    *(uint2*)(xph + 4 * tid) = p0;
    if (extra) {
      uint2 p1 = f4_to_h4(pre1f);
      *(uint2*)(xph + 4 * (tid + 512)) = p1;
    }
  }
  __syncthreads();

  for (int cs = 0; cs < 8; ++cs) {
    unsigned short* xpcur = xph + (cs & 1) * 3840;
    unsigned short* xpnxt = xph + ((cs + 1) & 1) * 3840;

    // issue next-stage loads FIRST (hide HBM latency under compute)
    uint2 t0 = make_uint2(0u, 0u), t1 = make_uint2(0u, 0u);
    if (cs < 7) {
      const float* xbn = x + (size_t)(n * CI + (cs + 1) * 32) * HW;
      t0 = f4_to_h4(load_slot20(xbn, h0, w0, tid, interior));
      if (extra) t1 = f4_to_h4(load_slot20(xbn, h0, w0, tid + 512, interior));
    }

    // compute current stage: 2 channel-iters, packed-f16 accumulate
    float* outb = out + ((size_t)(n * CI + cs * 32) * HS + oy) * WS_ + ox0;
#pragma unroll
    for (int it = 0; it < 2; ++it) {
      int cl = it * 16 + cslot;
      const unsigned short* p = xpcur + cl * 120 + py * 20 + cb0;
      unsigned aA = 0u, aB = 0u;        // packed f16 {sw0, sw1} accumulators
      ROWPK(A0.x, A0.y, A0.z, A0.w, A1.x, B0.x, B0.y, B0.z, B0.w, B1.x, p)
      ROWPK(A1.y, A1.z, A1.w, A2.x, A2.y, B1.y, B1.z, B1.w, B2.x, B2.y, p + 20)
      ROWPK(A2.z, A2.w, A3.x, A3.y, A3.z, B2.z, B2.w, B3.x, B3.y, B3.z, p + 40)
      ROWPK(A3.w, A4.x, A4.y, A4.z, A4.w, B3.w, B4.x, B4.y, B4.z, B4.w, p + 60)
      ROWPK(A5.x, A5.y, A5.z, A5.w, A6,   B5.x, B5.y, B5.z, B5.w, B6,   p + 80)
      __half2 hA = *reinterpret_cast<__half2*>(&aA);
      __half2 hB = *reinterpret_cast<__half2*>(&aB);
      float2 fA = __half22float2(hA);
      float2 fB = __half22float2(hB);
      *(float4*)(outb + (size_t)cl * HS * WS_) =
          make_float4(fA.x, fA.y, fB.x, fB.y);
    }

    // write next buffer + single barrier per stage
    if (cs < 7) {
      *(uint2*)(xpnxt + 4 * tid) = t0;
      if (extra) *(uint2*)(xpnxt + 4 * (tid + 512)) = t1;
      __syncthreads();
    }
  }
}

// ---------------------------------------------------------------------------
extern "C" void kernel_launch(void* const* d_in, const int* in_sizes, int n_in,
                              void* d_out, int out_size, void* d_ws,
                              size_t ws_size, hipStream_t stream) {
  const float* x      = (const float*)d_in[0];
  const float* w_comp = (const float*)d_in[1];
  const float* b_comp = (const float*)d_in[2];
  const float* w_enc  = (const float*)d_in[3];
  const float* b_enc  = (const float*)d_in[4];
  float* out = (float*)d_out;

  char* ws = (char*)d_ws;
  unsigned short* comp_cl = (unsigned short*)ws;                  // 2,097,152 B
  unsigned short* Aw1     = (unsigned short*)(ws + 2097152);      //    32,768 B
  unsigned short* Aw2     = (unsigned short*)(ws + 2129920);      //   129,024 B

  prep_kernel<<<dim3(316), 256, 0, stream>>>(w_comp, w_enc, Aw1, Aw2);
  conv1x1_mfma<<<dim3(512), 512, 0, stream>>>(x, Aw1, b_comp, comp_cl);
  fused_kernel<<<dim3(512), 512, 0, stream>>>(x, comp_cl, Aw2, b_enc, out);
}